// Round 4
// baseline (141.181 us; speedup 1.0000x reference)
//
#include <hip/hip_runtime.h>
#include <hip/hip_cooperative_groups.h>
#include <hip/hip_bf16.h>

namespace cg = cooperative_groups;

// out = exp(Q K^T) V, unnormalized. B=4, S=4096, D=64, fp32 in/out.
// Round 10: single fused cooperative kernel.
//  * prep + grid.sync + attn in ONE dispatch: removes 2 launches, the 20MB
//    partial round-trip, and the inter-kernel bubbles. 256 blocks x 512thr,
//    96KB LDS -> exactly 1 block/CU: cooperative co-residency guaranteed.
//  * Phase A: each block converts one K-or-V 128-row tile (prep2's verified
//    code, re-laned to 512 threads) + zeroes its 16KB slice of out.
//  * Phase B: round-8/9-verified attn loop (triple-buffer, counted vmcnt(4),
//    1 barrier/iter, permlane32_swap C->A transpose, exp2 prescaled-Q) with
//    the round-8-verified fp32-atomic epilogue (commutative add, bit-exact).
//  * Falls back to the round-9 three-kernel path if cooperative launch is
//    unavailable; attn_fallback covers non-standard shapes.

typedef short    s16x4 __attribute__((ext_vector_type(4)));
typedef short    s16x8 __attribute__((ext_vector_type(8)));
typedef _Float16 h16x8 __attribute__((ext_vector_type(8)));
typedef float    fx4   __attribute__((ext_vector_type(4)));
typedef float    fx16  __attribute__((ext_vector_type(16)));

constexpr int S = 4096, D = 64, BN = 128;
constexpr int QROWS = 128;                          // q-rows per block (attn)
constexpr int TILES = S / BN;                       // 32
constexpr int HALF_TILES = TILES / 2;               // 16 per kk-half
constexpr int TILE_SHORTS  = 16 * 512;              // 16KB per array per tile
constexpr int BATCH_SHORTS = TILES * TILE_SHORTS;   // 262144

__device__ __forceinline__ unsigned short f2bf(float x) {
    unsigned u = __float_as_uint(x);
    u = (u + 0x7FFFu + ((u >> 16) & 1u)) >> 16;   // RNE
    return (unsigned short)u;
}
__device__ __forceinline__ float bf2f(unsigned short h) {
    return __uint_as_float(((unsigned)h) << 16);
}
__device__ __forceinline__ unsigned short f2h(float x) {
    union { _Float16 h; unsigned short s; } u;
    u.h = (_Float16)x;
    return u.s;
}
__device__ __forceinline__ unsigned pack_bf16(float lo, float hi) {
    __hip_bfloat162 r = __float22bfloat162_rn(make_float2(lo, hi));
    union { __hip_bfloat162 b; unsigned u; } c;
    c.b = r;
    return c.u;
}
__device__ __forceinline__ float ex2(float x) {
#if __has_builtin(__builtin_amdgcn_exp2f)
    return __builtin_amdgcn_exp2f(x);
#else
    return exp2f(x);
#endif
}

// ================= fused cooperative kernel =================
__global__ __launch_bounds__(512, 2) void attn_fused(
    const float* __restrict__ q, const float* __restrict__ k,
    const float* __restrict__ v, unsigned short* __restrict__ kf,
    unsigned short* __restrict__ vf, float* __restrict__ out)
{
    __shared__ unsigned short smem[3 * 2 * TILE_SHORTS];   // 96KB

    const int tid = threadIdx.x;
    const int bid = blockIdx.x;

    // ---------- Phase A: prep one K-or-V tile + zero 16KB of out ----------
    {
        // zero: 256 blocks x 1024 float4 = 4MB
        float4 z = make_float4(0.f, 0.f, 0.f, 0.f);
        float4* oz = (float4*)out + (size_t)bid * 1024 + tid;
        oz[0] = z;
        oz[512] = z;

        const int which = bid & 1;            // 0 = K, 1 = V
        const int t     = (bid >> 1) & 31;
        const int b     = bid >> 6;
        const float* src = (which ? v : k) + ((size_t)b * S + t * BN) * D;
        unsigned short* tile = smem;          // 128*72 shorts = 18KB, fits

        #pragma unroll
        for (int i = 0; i < 4; ++i) {         // 2048 float4s / 512 thr
            int f   = i * 512 + tid;
            int row = f >> 4;
            int c4  = (f & 15) << 2;
            float4 x = *(const float4*)(src + row * D + c4);
            s16x4 o;
            if (which) o = (s16x4){(short)f2bf(x.x), (short)f2bf(x.y),
                                   (short)f2bf(x.z), (short)f2bf(x.w)};
            else       o = (s16x4){(short)f2h(x.x), (short)f2h(x.y),
                                   (short)f2h(x.z), (short)f2h(x.w)};
            *(s16x4*)&tile[row * 72 + c4] = o;
        }
        __syncthreads();

        const int lane = tid & 63;
        unsigned short* dst = (which ? vf : kf) + (size_t)b * BATCH_SHORTS + t * TILE_SHORTS;
        #pragma unroll
        for (int i = 0; i < 2; ++i) {
            int c = (tid >> 6) * 2 + i;       // 8 waves x 2 chunks = 16
            s16x8 o;
            if (which == 0) {
                int row = (c >> 2) * 32 + (lane & 31);
                int dc  = (c & 3) * 16 + (lane >> 5) * 8;
                o = *(const s16x8*)&tile[row * 72 + dc];     // b128, aligned
            } else {
                int r0 = (c >> 1) * 16 + (lane >> 5) * 8;
                int dc = (c & 1) * 32 + (lane & 31);
                #pragma unroll
                for (int j = 0; j < 8; ++j) o[j] = (short)tile[(r0 + j) * 72 + dc];
            }
            *(s16x8*)(dst + c * 512 + lane * 8) = o;         // coalesced b128
        }
    }

    // All kf/vf writes + out zeroing visible grid-wide after this.
    cg::this_grid().sync();

    // ---------- Phase B: attention main loop ----------
    const int lane = tid & 63, w = tid >> 6;
    const int h = lane >> 5, m5 = lane & 31;
    const int mh = w & 1, kkq = w >> 1;         // m-half (64 rows), kk-quarter
    const int slice = bid & 7;                  // -> XCD under %8 round-robin
    const int b = slice >> 1;                   // batch 0..3
    const int kh = slice & 1;                   // kk-half 0/1
    const int q0 = (bid >> 3) * QROWS;
    const int t0 = kh * HALF_TILES;

    const unsigned short* kfb = kf + (size_t)b * BATCH_SHORTS;
    const unsigned short* vfb = vf + (size_t)b * BATCH_SHORTS;

    // Q B-frags fp16, pre-scaled by log2(e) so exp(s) = exp2(s').
    const float LOG2E = 1.4426950408889634f;
    h16x8 qf[2][4];   // [mt][ks]
    #pragma unroll
    for (int mt = 0; mt < 2; ++mt) {
        const float* qrow = q + ((size_t)b * S + q0 + mh * 64 + mt * 32 + m5) * D + h * 8;
        #pragma unroll
        for (int ks = 0; ks < 4; ++ks) {
            float4 a = *(const float4*)(qrow + ks * 16);
            float4 c = *(const float4*)(qrow + ks * 16 + 4);
            qf[mt][ks] = (h16x8){
                (_Float16)(a.x * LOG2E), (_Float16)(a.y * LOG2E),
                (_Float16)(a.z * LOG2E), (_Float16)(a.w * LOG2E),
                (_Float16)(c.x * LOG2E), (_Float16)(c.y * LOG2E),
                (_Float16)(c.z * LOG2E), (_Float16)(c.w * LOG2E)};
        }
    }

    fx16 oacc[2][2] = {};   // [mt][dt]

    auto issue = [&](int t, int bi) {
        unsigned short* base = &smem[bi * 2 * TILE_SHORTS];
        #pragma unroll
        for (int ii = 0; ii < 4; ++ii) {                 // ii<2: K, else V
            int c = (ii & 1) * 8 + w;                    // chunk 0..15
            const unsigned short* g = (ii < 2 ? kfb : vfb)
                + (size_t)t * TILE_SHORTS + c * 512 + lane * 8;
            unsigned short* l = base + (ii < 2 ? 0 : TILE_SHORTS) + c * 512 + lane * 8;
            __builtin_amdgcn_global_load_lds(
                (const __attribute__((address_space(1))) unsigned int*)g,
                (__attribute__((address_space(3))) unsigned int*)l, 16, 0, 0);
        }
    };

    issue(t0 + 0, 0);
    issue(t0 + 1, 1);

    for (int i = 0; i < HALF_TILES; ++i) {
        const int bi = i % 3;
        // Tile i's 4 DMAs (this wave's) were issued TWO iterations ago; 4
        // loads for tile i+1 may still be in flight -> wait vmcnt(4), not 0.
        __asm__ volatile("" ::: "memory");
        if (i + 1 < HALF_TILES) {
            __builtin_amdgcn_s_waitcnt(0x0F74);   // vmcnt(4)
        } else {
            __builtin_amdgcn_s_waitcnt(0x0F70);   // vmcnt(0): last tile
        }
        __builtin_amdgcn_s_barrier();
        __asm__ volatile("" ::: "memory");
        if (i + 2 < HALF_TILES) issue(t0 + i + 2, (i + 2) % 3);

        const unsigned short* kb = &smem[bi * 2 * TILE_SHORTS];
        const unsigned short* vb = kb + TILE_SHORTS;

        // ---- GEMM1 (fp16 32x32x16): Sc^T[kk 32][m 32] x2 mt, d=64 ----
        fx16 sa[2] = {};
        #pragma unroll
        for (int ks = 0; ks < 4; ++ks) {
            h16x8 a = *(const h16x8*)(kb + (kkq * 4 + ks) * 512 + lane * 8);
            #pragma unroll
            for (int mt = 0; mt < 2; ++mt)
                sa[mt] = __builtin_amdgcn_mfma_f32_32x32x16_f16(a, qf[mt][ks], sa[mt], 0, 0, 0);
        }

        // ---- P = exp2(Sc^T') in regs, bf16-pair packed ----
        unsigned p01[2][8];
        #pragma unroll
        for (int mt = 0; mt < 2; ++mt)
            #pragma unroll
            for (int rp = 0; rp < 8; ++rp)
                p01[mt][rp] = pack_bf16(ex2(sa[mt][2 * rp]), ex2(sa[mt][2 * rp + 1]));

        // ---- C-layout -> GEMM2 A-layout: cross-half exchange ----
        union frag { unsigned u[4]; s16x8 v; };
        frag A[2][2];   // [mt][u]
        #pragma unroll
        for (int mt = 0; mt < 2; ++mt) {
#if __has_builtin(__builtin_amdgcn_permlane32_swap)
            typedef unsigned uix2 __attribute__((ext_vector_type(2)));
            uix2 r0 = __builtin_amdgcn_permlane32_swap(p01[mt][0], p01[mt][2], false, false);
            uix2 r1 = __builtin_amdgcn_permlane32_swap(p01[mt][1], p01[mt][3], false, false);
            A[mt][0].u[0] = r0.x; A[mt][0].u[1] = r1.x;
            A[mt][0].u[2] = r0.y; A[mt][0].u[3] = r1.y;
            uix2 r2 = __builtin_amdgcn_permlane32_swap(p01[mt][4], p01[mt][6], false, false);
            uix2 r3 = __builtin_amdgcn_permlane32_swap(p01[mt][5], p01[mt][7], false, false);
            A[mt][1].u[0] = r2.x; A[mt][1].u[1] = r3.x;
            A[mt][1].u[2] = r2.y; A[mt][1].u[3] = r3.y;
#else
            unsigned sw[8];
            #pragma unroll
            for (int rp = 0; rp < 8; ++rp)
                sw[rp] = (unsigned)__shfl_xor((int)p01[mt][rp], 32, 64);
            A[mt][0].u[0] = h ? sw[2]        : p01[mt][0];
            A[mt][0].u[1] = h ? sw[3]        : p01[mt][1];
            A[mt][0].u[2] = h ? p01[mt][2]   : sw[0];
            A[mt][0].u[3] = h ? p01[mt][3]   : sw[1];
            A[mt][1].u[0] = h ? sw[6]        : p01[mt][4];
            A[mt][1].u[1] = h ? sw[7]        : p01[mt][5];
            A[mt][1].u[2] = h ? p01[mt][6]   : sw[4];
            A[mt][1].u[3] = h ? p01[mt][7]   : sw[5];
#endif
        }

        // ---- GEMM2 (bf16 32x32x16): O += P*V over this wave's 32 kk ----
        #pragma unroll
        for (int u = 0; u < 2; ++u) {
            int ss = kkq * 2 + u;                        // 16-kk step in tile
            #pragma unroll
            for (int dt = 0; dt < 2; ++dt) {
                s16x8 vv = *(const s16x8*)(vb + (ss * 2 + dt) * 512 + lane * 8);
                #pragma unroll
                for (int mt = 0; mt < 2; ++mt)
                    oacc[mt][dt] = __builtin_amdgcn_mfma_f32_32x32x16_bf16(
                        A[mt][u].v, vv, oacc[mt][dt], 0, 0, 0);
            }
        }
    }

    // ---- epilogue: LDS-reduce 4 kk-quarters, then one atomicAdd per
    //      element (the 2 kk-half blocks accumulate commutatively). ----
    __syncthreads();                     // all DMA drained (vmcnt(0) last iter)
    float* scratch = (float*)smem;
    float* ob = out + (size_t)b * S * D;
    #pragma unroll
    for (int dt = 0; dt < 2; ++dt) {
        if (kkq > 0) {
            float* dst = scratch + (size_t)(mh * 3 + (kkq - 1)) * 2048;
            #pragma unroll
            for (int mt = 0; mt < 2; ++mt)
                #pragma unroll
                for (int r = 0; r < 16; ++r)
                    dst[(mt * 16 + r) * 64 + lane] = oacc[mt][dt][r];
        }
        __syncthreads();
        if (kkq == 0) {
            #pragma unroll
            for (int mt = 0; mt < 2; ++mt)
                #pragma unroll
                for (int r = 0; r < 16; ++r) {
                    float val = oacc[mt][dt][r];
                    #pragma unroll
                    for (int p = 0; p < 3; ++p)
                        val += scratch[(size_t)(mh * 3 + p) * 2048 + (mt * 16 + r) * 64 + lane];
                    int row = q0 + mh * 64 + mt * 32 + (r & 3) + 8 * (r >> 2) + 4 * h;
                    atomicAdd(&ob[(size_t)row * D + dt * 32 + m5], val);
                }
        }
        __syncthreads();
    }
}

// ================= fallback path (round-9 three-kernel) =================
__global__ __launch_bounds__(256) void prep2(
    const float* __restrict__ k, const float* __restrict__ v,
    unsigned short* __restrict__ kf, unsigned short* __restrict__ vf)
{
    __shared__ unsigned short tile[128 * 72];
    const int tid   = threadIdx.x;
    const int which = blockIdx.x & 1;
    const int t     = (blockIdx.x >> 1) & 31;
    const int b     = blockIdx.x >> 6;
    const float* src = (which ? v : k) + ((size_t)b * S + t * BN) * D;

    #pragma unroll
    for (int i = 0; i < 8; ++i) {
        int f   = i * 256 + tid;
        int row = f >> 4;
        int c4  = (f & 15) << 2;
        float4 x = *(const float4*)(src + row * D + c4);
        s16x4 o;
        if (which) o = (s16x4){(short)f2bf(x.x), (short)f2bf(x.y),
                               (short)f2bf(x.z), (short)f2bf(x.w)};
        else       o = (s16x4){(short)f2h(x.x), (short)f2h(x.y),
                               (short)f2h(x.z), (short)f2h(x.w)};
        *(s16x4*)&tile[row * 72 + c4] = o;
    }
    __syncthreads();

    const int lane = tid & 63;
    unsigned short* dst = (which ? vf : kf) + (size_t)b * BATCH_SHORTS + t * TILE_SHORTS;
    #pragma unroll
    for (int i = 0; i < 4; ++i) {
        int c = (tid >> 6) * 4 + i;
        s16x8 o;
        if (which == 0) {
            int row = (c >> 2) * 32 + (lane & 31);
            int dc  = (c & 3) * 16 + (lane >> 5) * 8;
            o = *(const s16x8*)&tile[row * 72 + dc];
        } else {
            int r0 = (c >> 1) * 16 + (lane >> 5) * 8;
            int dc = (c & 1) * 32 + (lane & 31);
            #pragma unroll
            for (int j = 0; j < 8; ++j) o[j] = (short)tile[(r0 + j) * 72 + dc];
        }
        *(s16x8*)(dst + c * 512 + lane * 8) = o;
    }
}

__global__ __launch_bounds__(512, 2) void attn_main4(
    const float* __restrict__ q, const unsigned short* __restrict__ kf,
    const unsigned short* __restrict__ vf, float* __restrict__ partial)
{
    __shared__ unsigned short smem[3 * 2 * TILE_SHORTS];

    const int tid = threadIdx.x, lane = tid & 63, w = tid >> 6;
    const int h = lane >> 5, m5 = lane & 31;
    const int mh = w & 1, kkq = w >> 1;
    const int bid = blockIdx.x;
    const int slice = bid & 7;
    const int b = slice >> 1;
    const int kh = slice & 1;
    const int q0 = (bid >> 3) * QROWS;
    const int t0 = kh * HALF_TILES;

    const unsigned short* kfb = kf + (size_t)b * BATCH_SHORTS;
    const unsigned short* vfb = vf + (size_t)b * BATCH_SHORTS;

    const float LOG2E = 1.4426950408889634f;
    h16x8 qf[2][4];
    #pragma unroll
    for (int mt = 0; mt < 2; ++mt) {
        const float* qrow = q + ((size_t)b * S + q0 + mh * 64 + mt * 32 + m5) * D + h * 8;
        #pragma unroll
        for (int ks = 0; ks < 4; ++ks) {
            float4 a = *(const float4*)(qrow + ks * 16);
            float4 c = *(const float4*)(qrow + ks * 16 + 4);
            qf[mt][ks] = (h16x8){
                (_Float16)(a.x * LOG2E), (_Float16)(a.y * LOG2E),
                (_Float16)(a.z * LOG2E), (_Float16)(a.w * LOG2E),
                (_Float16)(c.x * LOG2E), (_Float16)(c.y * LOG2E),
                (_Float16)(c.z * LOG2E), (_Float16)(c.w * LOG2E)};
        }
    }

    fx16 oacc[2][2] = {};

    auto issue = [&](int t, int bi) {
        unsigned short* base = &smem[bi * 2 * TILE_SHORTS];
        #pragma unroll
        for (int ii = 0; ii < 4; ++ii) {
            int c = (ii & 1) * 8 + w;
            const unsigned short* g = (ii < 2 ? kfb : vfb)
                + (size_t)t * TILE_SHORTS + c * 512 + lane * 8;
            unsigned short* l = base + (ii < 2 ? 0 : TILE_SHORTS) + c * 512 + lane * 8;
            __builtin_amdgcn_global_load_lds(
                (const __attribute__((address_space(1))) unsigned int*)g,
                (__attribute__((address_space(3))) unsigned int*)l, 16, 0, 0);
        }
    };

    issue(t0 + 0, 0);
    issue(t0 + 1, 1);

    for (int i = 0; i < HALF_TILES; ++i) {
        const int bi = i % 3;
        __asm__ volatile("" ::: "memory");
        if (i + 1 < HALF_TILES) {
            __builtin_amdgcn_s_waitcnt(0x0F74);
        } else {
            __builtin_amdgcn_s_waitcnt(0x0F70);
        }
        __builtin_amdgcn_s_barrier();
        __asm__ volatile("" ::: "memory");
        if (i + 2 < HALF_TILES) issue(t0 + i + 2, (i + 2) % 3);

        const unsigned short* kb = &smem[bi * 2 * TILE_SHORTS];
        const unsigned short* vb = kb + TILE_SHORTS;

        fx16 sa[2] = {};
        #pragma unroll
        for (int ks = 0; ks < 4; ++ks) {
            h16x8 a = *(const h16x8*)(kb + (kkq * 4 + ks) * 512 + lane * 8);
            #pragma unroll
            for (int mt = 0; mt < 2; ++mt)
                sa[mt] = __builtin_amdgcn_mfma_f32_32x32x16_f16(a, qf[mt][ks], sa[mt], 0, 0, 0);
        }

        unsigned p01[2][8];
        #pragma unroll
        for (int mt = 0; mt < 2; ++mt)
            #pragma unroll
            for (int rp = 0; rp < 8; ++rp)
                p01[mt][rp] = pack_bf16(ex2(sa[mt][2 * rp]), ex2(sa[mt][2 * rp + 1]));

        union frag { unsigned u[4]; s16x8 v; };
        frag A[2][2];
        #pragma unroll
        for (int mt = 0; mt < 2; ++mt) {
#if __has_builtin(__builtin_amdgcn_permlane32_swap)
            typedef unsigned uix2 __attribute__((ext_vector_type(2)));
            uix2 r0 = __builtin_amdgcn_permlane32_swap(p01[mt][0], p01[mt][2], false, false);
            uix2 r1 = __builtin_amdgcn_permlane32_swap(p01[mt][1], p01[mt][3], false, false);
            A[mt][0].u[0] = r0.x; A[mt][0].u[1] = r1.x;
            A[mt][0].u[2] = r0.y; A[mt][0].u[3] = r1.y;
            uix2 r2 = __builtin_amdgcn_permlane32_swap(p01[mt][4], p01[mt][6], false, false);
            uix2 r3 = __builtin_amdgcn_permlane32_swap(p01[mt][5], p01[mt][7], false, false);
            A[mt][1].u[0] = r2.x; A[mt][1].u[1] = r3.x;
            A[mt][1].u[2] = r2.y; A[mt][1].u[3] = r3.y;
#else
            unsigned sw[8];
            #pragma unroll
            for (int rp = 0; rp < 8; ++rp)
                sw[rp] = (unsigned)__shfl_xor((int)p01[mt][rp], 32, 64);
            A[mt][0].u[0] = h ? sw[2]        : p01[mt][0];
            A[mt][0].u[1] = h ? sw[3]        : p01[mt][1];
            A[mt][0].u[2] = h ? p01[mt][2]   : sw[0];
            A[mt][0].u[3] = h ? p01[mt][3]   : sw[1];
            A[mt][1].u[0] = h ? sw[6]        : p01[mt][4];
            A[mt][1].u[1] = h ? sw[7]        : p01[mt][5];
            A[mt][1].u[2] = h ? p01[mt][6]   : sw[4];
            A[mt][1].u[3] = h ? p01[mt][7]   : sw[5];
#endif
        }

        #pragma unroll
        for (int u = 0; u < 2; ++u) {
            int ss = kkq * 2 + u;
            #pragma unroll
            for (int dt = 0; dt < 2; ++dt) {
                s16x8 vv = *(const s16x8*)(vb + (ss * 2 + dt) * 512 + lane * 8);
                #pragma unroll
                for (int mt = 0; mt < 2; ++mt)
                    oacc[mt][dt] = __builtin_amdgcn_mfma_f32_32x32x16_bf16(
                        A[mt][u].v, vv, oacc[mt][dt], 0, 0, 0);
            }
        }
    }

    __syncthreads();
    float* scratch = (float*)smem;
    float* pout = partial + ((size_t)kh * 4 + b) * S * D;
    #pragma unroll
    for (int dt = 0; dt < 2; ++dt) {
        if (kkq > 0) {
            float* dst = scratch + (size_t)(mh * 3 + (kkq - 1)) * 2048;
            #pragma unroll
            for (int mt = 0; mt < 2; ++mt)
                #pragma unroll
                for (int r = 0; r < 16; ++r)
                    dst[(mt * 16 + r) * 64 + lane] = oacc[mt][dt][r];
        }
        __syncthreads();
        if (kkq == 0) {
            #pragma unroll
            for (int mt = 0; mt < 2; ++mt)
                #pragma unroll
                for (int r = 0; r < 16; ++r) {
                    float val = oacc[mt][dt][r];
                    #pragma unroll
                    for (int p = 0; p < 3; ++p)
                        val += scratch[(size_t)(mh * 3 + p) * 2048 + (mt * 16 + r) * 64 + lane];
                    int row = q0 + mh * 64 + mt * 32 + (r & 3) + 8 * (r >> 2) + 4 * h;
                    pout[(size_t)row * D + dt * 32 + m5] = val;
                }
        }
        __syncthreads();
    }
}

__global__ __launch_bounds__(256) void reduce_out(
    const float4* __restrict__ p0, const float4* __restrict__ p1,
    float4* __restrict__ o, int n4)
{
    int i = blockIdx.x * 256 + threadIdx.x;
    if (i < n4) {
        float4 a = p0[i], b = p1[i];
        o[i] = make_float4(a.x + b.x, a.y + b.y, a.z + b.z, a.w + b.w);
    }
}

// ---------------- fallback (known-good round-2 kernel) ----------------
__global__ __launch_bounds__(1024) void attn_fallback(
    const float* __restrict__ q, const float* __restrict__ k,
    const float* __restrict__ v, float* __restrict__ out)
{
    __shared__ unsigned short Kh[64][72];
    __shared__ unsigned short Kl[64][72];
    __shared__ unsigned short Vt[64][68];
    __shared__ unsigned short Pf[64][72];

    const int tid = threadIdx.x, lane = tid & 63, wave = tid >> 6;
    const int quad = lane >> 4, tq = lane & 15;
    const int kkb = wave & 3, mba = wave >> 2;
    const int b = blockIdx.y, q0 = blockIdx.x * 64;
    const float* qb = q + (size_t)b * S * D;
    const float* kb = k + (size_t)b * S * D;
    const float* vb = v + (size_t)b * S * D;
    float* ob = out + (size_t)b * S * D;

    s16x8 qh[2], ql[2];
    {
        const float* qrow = qb + (size_t)(q0 + mba * 16 + tq) * D;
        #pragma unroll
        for (int ks = 0; ks < 2; ++ks) {
            const float* src = qrow + ks * 32 + quad * 8;
            float4 f0 = *(const float4*)src;
            float4 f1 = *(const float4*)(src + 4);
            float f[8] = {f0.x, f0.y, f0.z, f0.w, f1.x, f1.y, f1.z, f1.w};
            #pragma unroll
            for (int j = 0; j < 8; ++j) {
                unsigned short hh = f2bf(f[j]);
                qh[ks][j] = (short)hh;
                ql[ks][j] = (short)f2bf(f[j] - bf2f(hh));
            }
        }
    }
    fx4 oacc = {0.f, 0.f, 0.f, 0.f};
    const int krow = tid >> 4, kc4 = (tid & 15) << 2;
    const int vd = tid & 63, vk = (tid >> 6) << 2;

    for (int t = 0; t < S / 64; ++t) {
        __syncthreads();
        const float* kt = kb + (size_t)(t * 64 + krow) * D;
        const float* vt = vb + (size_t)(t * 64 + vk) * D;
        {
            float4 kv = *(const float4*)(kt + kc4);
            unsigned short h0 = f2bf(kv.x), h1 = f2bf(kv.y), h2 = f2bf(kv.z), h3 = f2bf(kv.w);
            s16x4 a = {(short)h0, (short)h1, (short)h2, (short)h3};
            s16x4 l4 = {(short)f2bf(kv.x - bf2f(h0)), (short)f2bf(kv.y - bf2f(h1)),
                        (short)f2bf(kv.z - bf2f(h2)), (short)f2bf(kv.w - bf2f(h3))};
            *(s16x4*)&Kh[krow][kc4] = a;
            *(s16x4*)&Kl[krow][kc4] = l4;
            const float* vs = vt + vd;
            s16x4 vv = {(short)f2bf(vs[0]), (short)f2bf(vs[D]),
                        (short)f2bf(vs[2 * D]), (short)f2bf(vs[3 * D])};
            *(s16x4*)&Vt[vd][vk] = vv;
        }
        __syncthreads();
        fx4 sacc = {0.f, 0.f, 0.f, 0.f};
        #pragma unroll
        for (int ks = 0; ks < 2; ++ks) {
            s16x8 kah = *(const s16x8*)&Kh[kkb * 16 + tq][ks * 32 + quad * 8];
            s16x8 kal = *(const s16x8*)&Kl[kkb * 16 + tq][ks * 32 + quad * 8];
            sacc = __builtin_amdgcn_mfma_f32_16x16x32_bf16(kah, qh[ks], sacc, 0, 0, 0);
            sacc = __builtin_amdgcn_mfma_f32_16x16x32_bf16(kah, ql[ks], sacc, 0, 0, 0);
            sacc = __builtin_amdgcn_mfma_f32_16x16x32_bf16(kal, qh[ks], sacc, 0, 0, 0);
        }
        s16x4 pp = {(short)f2bf(__expf(sacc[0])), (short)f2bf(__expf(sacc[1])),
                    (short)f2bf(__expf(sacc[2])), (short)f2bf(__expf(sacc[3]))};
        *(s16x4*)&Pf[mba * 16 + tq][kkb * 16 + (quad << 2)] = pp;
        __syncthreads();
        #pragma unroll
        for (int ks = 0; ks < 2; ++ks) {
            s16x8 pa = *(const s16x8*)&Pf[mba * 16 + tq][ks * 32 + quad * 8];
            const unsigned short* vr = &Vt[kkb * 16 + tq][ks * 32 + quad * 8];
            s16x4 va = *(const s16x4*)vr;
            s16x4 vb2 = *(const s16x4*)(vr + 4);
            s16x8 vfull = __builtin_shufflevector(va, vb2, 0, 1, 2, 3, 4, 5, 6, 7);
            oacc = __builtin_amdgcn_mfma_f32_16x16x32_bf16(pa, vfull, oacc, 0, 0, 0);
        }
    }
    #pragma unroll
    for (int r = 0; r < 4; ++r)
        ob[(size_t)(q0 + mba * 16 + quad * 4 + r) * D + kkb * 16 + tq] = oacc[r];
}

extern "C" void kernel_launch(void* const* d_in, const int* in_sizes, int n_in,
                              void* d_out, int out_size, void* d_ws, size_t ws_size,
                              hipStream_t stream) {
    const float* q = (const float*)d_in[0];
    const float* k = (const float*)d_in[1];
    const float* v = (const float*)d_in[2];
    float* out = (float*)d_out;
    const int nbatch = in_sizes[0] / (S * D);   // 4
    const size_t elems = (size_t)nbatch * S * D;

    // ws: kf (fp16, 2MB) | vf (bf16, 2MB) | partial[2] (fp32, 8MB) = 12MB
    const size_t need = elems * 2 * 2 + elems * 2 * 4;
    if (nbatch == 4 && ws_size >= need && d_ws != nullptr) {
        unsigned short* kf = (unsigned short*)d_ws;
        unsigned short* vf = kf + elems;
        float* partial = (float*)(vf + elems);

        const float* qa = q; const float* ka = k; const float* va = v;
        unsigned short* kfa = kf; unsigned short* vfa = vf; float* outa = out;
        void* args[] = {(void*)&qa, (void*)&ka, (void*)&va,
                        (void*)&kfa, (void*)&vfa, (void*)&outa};
        hipError_t err = hipLaunchCooperativeKernel(
            (void*)attn_fused, dim3(256), dim3(512), args, 0, stream);
        if (err != hipSuccess) {
            // three-kernel fallback (round-9 verified path)
            prep2<<<nbatch * TILES * 2, 256, 0, stream>>>(k, v, kf, vf);
            attn_main4<<<256, 512, 0, stream>>>(q, kf, vf, partial);
            const int n4 = (int)(elems / 4);
            reduce_out<<<(n4 + 255) / 256, 256, 0, stream>>>(
                (const float4*)partial, (const float4*)(partial + elems),
                (float4*)out, n4);
        }
    } else {
        dim3 grid(S / 64, nbatch);
        attn_fallback<<<grid, 1024, 0, stream>>>(q, k, v, out);
    }
}

// Round 6
// 120.705 us; speedup vs baseline: 1.1696x; 1.1696x over previous
//
#include <hip/hip_runtime.h>
#include <hip/hip_bf16.h>

// out = exp(Q K^T) V, unnormalized. B=4, S=4096, D=64, fp32 in/out.
// Round 12 (= round 11 resubmitted after infra failure; never measured).
// Occupancy doubling per R10 counters (latency-bound at 20% occupancy):
//  * R10 fused-coop probe measured: MfmaUtil 9.9%, VALUBusy 15.8%, Occ 20.4%,
//    HBM 3%, conflicts 0 -> all pipes idle; barrier/latency-bound at
//    1 block/CU (grid 256 AND 96KB LDS both capped it). Coop launch itself
//    cost ~75us of overhead -> dropped.
//  * kk split 4-ways: 512 blocks x 8 tiles = 2 blocks/CU; 64KB double-buffer
//    (R6-verified structure: vmcnt(0) + 1 barrier/iter, issue-next after).
//    When one block drains DMA at the barrier, the other block's 8 waves
//    compute -> cross-block overlap replaces the missing pipeline depth.
//  * __launch_bounds__(512,4): 4 waves/SIMD target, VGPR cap 128 (was 88).
//  * Epilogue: fp32 atomicAdd into prep2-zeroed out (4 kh contributions,
//    commutative -> bit-exact vs tree reduce).
//  * Unchanged: K fp16/V bf16 frag pre-pack, permlane32_swap C->A transpose,
//    exp2 with log2(e)-prescaled Q.

typedef short    s16x4 __attribute__((ext_vector_type(4)));
typedef short    s16x8 __attribute__((ext_vector_type(8)));
typedef _Float16 h16x8 __attribute__((ext_vector_type(8)));
typedef float    fx4   __attribute__((ext_vector_type(4)));
typedef float    fx16  __attribute__((ext_vector_type(16)));

constexpr int S = 4096, D = 64, BN = 128;
constexpr int QROWS = 128;                          // q-rows per block
constexpr int TILES = S / BN;                       // 32
constexpr int QTR_TILES = TILES / 4;                // 8 per kk-quarter-range
constexpr int TILE_SHORTS  = 16 * 512;              // 16KB per array per tile
constexpr int BATCH_SHORTS = TILES * TILE_SHORTS;   // 262144

__device__ __forceinline__ unsigned short f2bf(float x) {
    unsigned u = __float_as_uint(x);
    u = (u + 0x7FFFu + ((u >> 16) & 1u)) >> 16;   // RNE
    return (unsigned short)u;
}
__device__ __forceinline__ float bf2f(unsigned short h) {
    return __uint_as_float(((unsigned)h) << 16);
}
__device__ __forceinline__ unsigned short f2h(float x) {
    union { _Float16 h; unsigned short s; } u;
    u.h = (_Float16)x;
    return u.s;
}
__device__ __forceinline__ unsigned pack_bf16(float lo, float hi) {
    __hip_bfloat162 r = __float22bfloat162_rn(make_float2(lo, hi));
    union { __hip_bfloat162 b; unsigned u; } c;
    c.b = r;
    return c.u;
}
__device__ __forceinline__ float ex2(float x) {
#if __has_builtin(__builtin_amdgcn_exp2f)
    return __builtin_amdgcn_exp2f(x);
#else
    return exp2f(x);
#endif
}

// -------- prep: K -> fp16 A-frag order, V -> bf16 B-frag order (32x32x16) ---
// Also zeroes a 16KB slice of out per block (for the atomic epilogue).
// K chunk c = kkq*4+ks : [lane][j] = K[t*128 + kkq*32 + (lane&31)][ks*16 + (lane>>5)*8 + j]
// V chunk c = ss*2+dt  : [lane][j] = V[t*128 + ss*16 + (lane>>5)*8 + j][dt*32 + (lane&31)]
__global__ __launch_bounds__(256) void prep2(
    const float* __restrict__ k, const float* __restrict__ v,
    unsigned short* __restrict__ kf, unsigned short* __restrict__ vf,
    float* __restrict__ out)
{
    __shared__ unsigned short tile[128 * 72];   // row stride 72 halves (pad)
    const int tid   = threadIdx.x;
    const int which = blockIdx.x & 1;           // 0 = K, 1 = V
    const int t     = (blockIdx.x >> 1) & 31;
    const int b     = blockIdx.x >> 6;
    const float* src = (which ? v : k) + ((size_t)b * S + t * BN) * D;

    // zero 16KB of out: 256 blocks x 1024 float4 = 4MB total
    {
        float4 z = make_float4(0.f, 0.f, 0.f, 0.f);
        float4* oz = (float4*)out + (size_t)blockIdx.x * 1024 + tid;
        #pragma unroll
        for (int i = 0; i < 4; ++i) oz[i * 256] = z;
    }

    #pragma unroll
    for (int i = 0; i < 8; ++i) {               // coalesced: 2048 float4s/block
        int f   = i * 256 + tid;
        int row = f >> 4;
        int c4  = (f & 15) << 2;
        float4 x = *(const float4*)(src + row * D + c4);
        s16x4 o;
        if (which) o = (s16x4){(short)f2bf(x.x), (short)f2bf(x.y),
                               (short)f2bf(x.z), (short)f2bf(x.w)};
        else       o = (s16x4){(short)f2h(x.x), (short)f2h(x.y),
                               (short)f2h(x.z), (short)f2h(x.w)};
        *(s16x4*)&tile[row * 72 + c4] = o;
    }
    __syncthreads();

    const int lane = tid & 63;
    unsigned short* dst = (which ? vf : kf) + (size_t)b * BATCH_SHORTS + t * TILE_SHORTS;
    #pragma unroll
    for (int i = 0; i < 4; ++i) {
        int c = (tid >> 6) * 4 + i;             // chunk 0..15
        s16x8 o;
        if (which == 0) {
            int row = (c >> 2) * 32 + (lane & 31);
            int dc  = (c & 3) * 16 + (lane >> 5) * 8;
            o = *(const s16x8*)&tile[row * 72 + dc];     // b128, aligned
        } else {
            int r0 = (c >> 1) * 16 + (lane >> 5) * 8;
            int dc = (c & 1) * 32 + (lane & 31);
            #pragma unroll
            for (int j = 0; j < 8; ++j) o[j] = (short)tile[(r0 + j) * 72 + dc];
        }
        *(s16x8*)(dst + c * 512 + lane * 8) = o;         // coalesced b128
    }
}

// ---------------- main: 128 q-rows, one kk-QUARTER (8 tiles) per block -----
// 512 blocks = 2 blocks/CU (64KB LDS each). bid&15 = (b,kh) slice: under %8
// round-robin each XCD serves 2 slices (~1MB working set, L2-resident).
// Atomic fp32 accumulation into pre-zeroed out (4 kh writers, commutative).
__global__ __launch_bounds__(512, 4) void attn_main5(
    const float* __restrict__ q, const unsigned short* __restrict__ kf,
    const unsigned short* __restrict__ vf, float* __restrict__ out)
{
    __shared__ unsigned short smem[2 * 2 * TILE_SHORTS];   // 64KB: 2 x (K|V)

    const int tid = threadIdx.x, lane = tid & 63, w = tid >> 6;
    const int h = lane >> 5, m5 = lane & 31;
    const int mh = w & 1, kkq = w >> 1;         // m-half (64 rows), kk-quarter
    const int bid = blockIdx.x;
    const int slice = bid & 15;
    const int b = slice >> 2;                   // batch 0..3
    const int kh = slice & 3;                   // kk quarter-range 0..3
    const int q0 = (bid >> 4) * QROWS;
    const int t0 = kh * QTR_TILES;

    const unsigned short* kfb = kf + (size_t)b * BATCH_SHORTS;
    const unsigned short* vfb = vf + (size_t)b * BATCH_SHORTS;

    // Q B-frags fp16, pre-scaled by log2(e) so exp(s) = exp2(s').
    const float LOG2E = 1.4426950408889634f;
    h16x8 qf[2][4];   // [mt][ks]
    #pragma unroll
    for (int mt = 0; mt < 2; ++mt) {
        const float* qrow = q + ((size_t)b * S + q0 + mh * 64 + mt * 32 + m5) * D + h * 8;
        #pragma unroll
        for (int ks = 0; ks < 4; ++ks) {
            float4 a = *(const float4*)(qrow + ks * 16);
            float4 c = *(const float4*)(qrow + ks * 16 + 4);
            qf[mt][ks] = (h16x8){
                (_Float16)(a.x * LOG2E), (_Float16)(a.y * LOG2E),
                (_Float16)(a.z * LOG2E), (_Float16)(a.w * LOG2E),
                (_Float16)(c.x * LOG2E), (_Float16)(c.y * LOG2E),
                (_Float16)(c.z * LOG2E), (_Float16)(c.w * LOG2E)};
        }
    }

    fx16 oacc[2][2] = {};   // [mt][dt]

    auto issue = [&](int t, int bi) {
        unsigned short* base = &smem[bi * 2 * TILE_SHORTS];
        #pragma unroll
        for (int ii = 0; ii < 4; ++ii) {                 // ii<2: K, else V
            int c = (ii & 1) * 8 + w;                    // chunk 0..15
            const unsigned short* g = (ii < 2 ? kfb : vfb)
                + (size_t)t * TILE_SHORTS + c * 512 + lane * 8;
            unsigned short* l = base + (ii < 2 ? 0 : TILE_SHORTS) + c * 512 + lane * 8;
            __builtin_amdgcn_global_load_lds(
                (const __attribute__((address_space(1))) unsigned int*)g,
                (__attribute__((address_space(3))) unsigned int*)l, 16, 0, 0);
        }
    };

    issue(t0, 0);

    for (int i = 0; i < QTR_TILES; ++i) {
        const int bi = i & 1;
        // Wait own 4 DMAs of tile i (issued one phase ago); barrier proves
        // all waves done reading buf bi^1 -> safe to refill it.
        __asm__ volatile("" ::: "memory");
        __builtin_amdgcn_s_waitcnt(0x0F70);   // vmcnt(0)
        __builtin_amdgcn_s_barrier();
        __asm__ volatile("" ::: "memory");
        if (i + 1 < QTR_TILES) issue(t0 + i + 1, bi ^ 1);

        const unsigned short* kb = &smem[bi * 2 * TILE_SHORTS];
        const unsigned short* vb = kb + TILE_SHORTS;

        // ---- GEMM1 (fp16 32x32x16): Sc^T[kk 32][m 32] x2 mt, d=64 ----
        fx16 sa[2] = {};
        #pragma unroll
        for (int ks = 0; ks < 4; ++ks) {
            h16x8 a = *(const h16x8*)(kb + (kkq * 4 + ks) * 512 + lane * 8);
            #pragma unroll
            for (int mt = 0; mt < 2; ++mt)
                sa[mt] = __builtin_amdgcn_mfma_f32_32x32x16_f16(a, qf[mt][ks], sa[mt], 0, 0, 0);
        }

        // ---- P = exp2(Sc^T') in regs, bf16-pair packed ----
        unsigned p01[2][8];
        #pragma unroll
        for (int mt = 0; mt < 2; ++mt)
            #pragma unroll
            for (int rp = 0; rp < 8; ++rp)
                p01[mt][rp] = pack_bf16(ex2(sa[mt][2 * rp]), ex2(sa[mt][2 * rp + 1]));

        // ---- C-layout -> GEMM2 A-layout: cross-half exchange ----
        union frag { unsigned u[4]; s16x8 v; };
        frag A[2][2];   // [mt][u]
        #pragma unroll
        for (int mt = 0; mt < 2; ++mt) {
#if __has_builtin(__builtin_amdgcn_permlane32_swap)
            typedef unsigned uix2 __attribute__((ext_vector_type(2)));
            uix2 r0 = __builtin_amdgcn_permlane32_swap(p01[mt][0], p01[mt][2], false, false);
            uix2 r1 = __builtin_amdgcn_permlane32_swap(p01[mt][1], p01[mt][3], false, false);
            A[mt][0].u[0] = r0.x; A[mt][0].u[1] = r1.x;
            A[mt][0].u[2] = r0.y; A[mt][0].u[3] = r1.y;
            uix2 r2 = __builtin_amdgcn_permlane32_swap(p01[mt][4], p01[mt][6], false, false);
            uix2 r3 = __builtin_amdgcn_permlane32_swap(p01[mt][5], p01[mt][7], false, false);
            A[mt][1].u[0] = r2.x; A[mt][1].u[1] = r3.x;
            A[mt][1].u[2] = r2.y; A[mt][1].u[3] = r3.y;
#else
            unsigned sw[8];
            #pragma unroll
            for (int rp = 0; rp < 8; ++rp)
                sw[rp] = (unsigned)__shfl_xor((int)p01[mt][rp], 32, 64);
            A[mt][0].u[0] = h ? sw[2]        : p01[mt][0];
            A[mt][0].u[1] = h ? sw[3]        : p01[mt][1];
            A[mt][0].u[2] = h ? p01[mt][2]   : sw[0];
            A[mt][0].u[3] = h ? p01[mt][3]   : sw[1];
            A[mt][1].u[0] = h ? sw[6]        : p01[mt][4];
            A[mt][1].u[1] = h ? sw[7]        : p01[mt][5];
            A[mt][1].u[2] = h ? p01[mt][6]   : sw[4];
            A[mt][1].u[3] = h ? p01[mt][7]   : sw[5];
#endif
        }

        // ---- GEMM2 (bf16 32x32x16): O += P*V over this wave's 32 kk ----
        #pragma unroll
        for (int u = 0; u < 2; ++u) {
            int ss = kkq * 2 + u;                        // 16-kk step in tile
            #pragma unroll
            for (int dt = 0; dt < 2; ++dt) {
                s16x8 vv = *(const s16x8*)(vb + (ss * 2 + dt) * 512 + lane * 8);
                #pragma unroll
                for (int mt = 0; mt < 2; ++mt)
                    oacc[mt][dt] = __builtin_amdgcn_mfma_f32_32x32x16_bf16(
                        A[mt][u].v, vv, oacc[mt][dt], 0, 0, 0);
            }
        }
    }

    // ---- epilogue: LDS-reduce 4 kk-quarters, then one atomicAdd per
    //      element (the 4 kh-range blocks accumulate commutatively). ----
    __syncthreads();                     // all DMA drained (vmcnt(0) each iter)
    float* scratch = (float*)smem;
    float* ob = out + (size_t)b * S * D;
    #pragma unroll
    for (int dt = 0; dt < 2; ++dt) {
        if (kkq > 0) {
            float* dst = scratch + (size_t)(mh * 3 + (kkq - 1)) * 2048;
            #pragma unroll
            for (int mt = 0; mt < 2; ++mt)
                #pragma unroll
                for (int r = 0; r < 16; ++r)
                    dst[(mt * 16 + r) * 64 + lane] = oacc[mt][dt][r];
        }
        __syncthreads();
        if (kkq == 0) {
            #pragma unroll
            for (int mt = 0; mt < 2; ++mt)
                #pragma unroll
                for (int r = 0; r < 16; ++r) {
                    float val = oacc[mt][dt][r];
                    #pragma unroll
                    for (int p = 0; p < 3; ++p)
                        val += scratch[(size_t)(mh * 3 + p) * 2048 + (mt * 16 + r) * 64 + lane];
                    int row = q0 + mh * 64 + mt * 32 + (r & 3) + 8 * (r >> 2) + 4 * h;
                    atomicAdd(&ob[(size_t)row * D + dt * 32 + m5], val);
                }
        }
        __syncthreads();
    }
}

// ---------------- fallback (known-good round-2 kernel) ----------------
__global__ __launch_bounds__(1024) void attn_fallback(
    const float* __restrict__ q, const float* __restrict__ k,
    const float* __restrict__ v, float* __restrict__ out)
{
    __shared__ unsigned short Kh[64][72];
    __shared__ unsigned short Kl[64][72];
    __shared__ unsigned short Vt[64][68];
    __shared__ unsigned short Pf[64][72];

    const int tid = threadIdx.x, lane = tid & 63, wave = tid >> 6;
    const int quad = lane >> 4, tq = lane & 15;
    const int kkb = wave & 3, mba = wave >> 2;
    const int b = blockIdx.y, q0 = blockIdx.x * 64;
    const float* qb = q + (size_t)b * S * D;
    const float* kb = k + (size_t)b * S * D;
    const float* vb = v + (size_t)b * S * D;
    float* ob = out + (size_t)b * S * D;

    s16x8 qh[2], ql[2];
    {
        const float* qrow = qb + (size_t)(q0 + mba * 16 + tq) * D;
        #pragma unroll
        for (int ks = 0; ks < 2; ++ks) {
            const float* src = qrow + ks * 32 + quad * 8;
            float4 f0 = *(const float4*)src;
            float4 f1 = *(const float4*)(src + 4);
            float f[8] = {f0.x, f0.y, f0.z, f0.w, f1.x, f1.y, f1.z, f1.w};
            #pragma unroll
            for (int j = 0; j < 8; ++j) {
                unsigned short hh = f2bf(f[j]);
                qh[ks][j] = (short)hh;
                ql[ks][j] = (short)f2bf(f[j] - bf2f(hh));
            }
        }
    }
    fx4 oacc = {0.f, 0.f, 0.f, 0.f};
    const int krow = tid >> 4, kc4 = (tid & 15) << 2;
    const int vd = tid & 63, vk = (tid >> 6) << 2;

    for (int t = 0; t < S / 64; ++t) {
        __syncthreads();
        const float* kt = kb + (size_t)(t * 64 + krow) * D;
        const float* vt = vb + (size_t)(t * 64 + vk) * D;
        {
            float4 kv = *(const float4*)(kt + kc4);
            unsigned short h0 = f2bf(kv.x), h1 = f2bf(kv.y), h2 = f2bf(kv.z), h3 = f2bf(kv.w);
            s16x4 a = {(short)h0, (short)h1, (short)h2, (short)h3};
            s16x4 l4 = {(short)f2bf(kv.x - bf2f(h0)), (short)f2bf(kv.y - bf2f(h1)),
                        (short)f2bf(kv.z - bf2f(h2)), (short)f2bf(kv.w - bf2f(h3))};
            *(s16x4*)&Kh[krow][kc4] = a;
            *(s16x4*)&Kl[krow][kc4] = l4;
            const float* vs = vt + vd;
            s16x4 vv = {(short)f2bf(vs[0]), (short)f2bf(vs[D]),
                        (short)f2bf(vs[2 * D]), (short)f2bf(vs[3 * D])};
            *(s16x4*)&Vt[vd][vk] = vv;
        }
        __syncthreads();
        fx4 sacc = {0.f, 0.f, 0.f, 0.f};
        #pragma unroll
        for (int ks = 0; ks < 2; ++ks) {
            s16x8 kah = *(const s16x8*)&Kh[kkb * 16 + tq][ks * 32 + quad * 8];
            s16x8 kal = *(const s16x8*)&Kl[kkb * 16 + tq][ks * 32 + quad * 8];
            sacc = __builtin_amdgcn_mfma_f32_16x16x32_bf16(kah, qh[ks], sacc, 0, 0, 0);
            sacc = __builtin_amdgcn_mfma_f32_16x16x32_bf16(kah, ql[ks], sacc, 0, 0, 0);
            sacc = __builtin_amdgcn_mfma_f32_16x16x32_bf16(kal, qh[ks], sacc, 0, 0, 0);
        }
        s16x4 pp = {(short)f2bf(__expf(sacc[0])), (short)f2bf(__expf(sacc[1])),
                    (short)f2bf(__expf(sacc[2])), (short)f2bf(__expf(sacc[3]))};
        *(s16x4*)&Pf[mba * 16 + tq][kkb * 16 + (quad << 2)] = pp;
        __syncthreads();
        #pragma unroll
        for (int ks = 0; ks < 2; ++ks) {
            s16x8 pa = *(const s16x8*)&Pf[mba * 16 + tq][ks * 32 + quad * 8];
            const unsigned short* vr = &Vt[kkb * 16 + tq][ks * 32 + quad * 8];
            s16x4 va = *(const s16x4*)vr;
            s16x4 vb2 = *(const s16x4*)(vr + 4);
            s16x8 vfull = __builtin_shufflevector(va, vb2, 0, 1, 2, 3, 4, 5, 6, 7);
            oacc = __builtin_amdgcn_mfma_f32_16x16x32_bf16(pa, vfull, oacc, 0, 0, 0);
        }
    }
    #pragma unroll
    for (int r = 0; r < 4; ++r)
        ob[(size_t)(q0 + mba * 16 + quad * 4 + r) * D + kkb * 16 + tq] = oacc[r];
}

extern "C" void kernel_launch(void* const* d_in, const int* in_sizes, int n_in,
                              void* d_out, int out_size, void* d_ws, size_t ws_size,
                              hipStream_t stream) {
    const float* q = (const float*)d_in[0];
    const float* k = (const float*)d_in[1];
    const float* v = (const float*)d_in[2];
    float* out = (float*)d_out;
    const int nbatch = in_sizes[0] / (S * D);   // 4
    const size_t elems = (size_t)nbatch * S * D;

    // ws: kf (fp16, 2MB) | vf (bf16, 2MB) = 4MB
    const size_t need = elems * 2 * 2;
    if (nbatch == 4 && ws_size >= need && d_ws != nullptr) {
        unsigned short* kf = (unsigned short*)d_ws;
        unsigned short* vf = kf + elems;

        prep2<<<nbatch * TILES * 2, 256, 0, stream>>>(k, v, kf, vf, out);
        attn_main5<<<512, 512, 0, stream>>>(q, kf, vf, out);
    } else {
        dim3 grid(S / 64, nbatch);
        attn_fallback<<<grid, 1024, 0, stream>>>(q, k, v, out);
    }
}

// Round 7
// 93.724 us; speedup vs baseline: 1.5064x; 1.2879x over previous
//
#include <hip/hip_runtime.h>
#include <hip/hip_bf16.h>

// out = exp(Q K^T) V, unnormalized. B=4, S=4096, D=64, fp32 in/out.
// Round 13: revert to the verified-best R6 structure (91.9us) + split-wait.
// Post-mortem of R11 (counters): occupancy 20->37% did NOT raise MfmaUtil
// (~11% both); the 4-way cross-XCD atomic epilogue amplified writes 4.3x
// (70MB vs 16MB payload) and regressed the kernel 45->59us. Reverted: 256
// blocks (1/CU), grid(32,4,2) (z-order temporally separates kh writers),
// partial[2]+reduce_out epilogue (streaming, no RMW).
// ONE change vs R6: per-iter K/V split-wait using in-order vmcnt retirement.
//   Each wave issues K,K,V,V per tile. Old: vmcnt(0)+barrier (waits V too).
//   New: vmcnt(2)+barrier -> GEMM1 may read K while V still flies;
//        issue(i+1); GEMM1+exp+transpose;
//        vmcnt(4)+barrier -> V(i) landed (4 newer = tile i+1's loads);
//        GEMM2 reads V. Full drain only on the last iteration.
//   V-latency + next-tile DMA hide under the ~600cyc GEMM1/exp phase.

typedef short    s16x4 __attribute__((ext_vector_type(4)));
typedef short    s16x8 __attribute__((ext_vector_type(8)));
typedef _Float16 h16x8 __attribute__((ext_vector_type(8)));
typedef float    fx4   __attribute__((ext_vector_type(4)));
typedef float    fx16  __attribute__((ext_vector_type(16)));

constexpr int S = 4096, D = 64, BN = 128;
constexpr int QROWS = 128;                          // q-rows per block (main4)
constexpr int TILES = S / BN;                       // 32
constexpr int HALF_TILES = TILES / 2;               // 16 per kk-half
constexpr int TILE_SHORTS  = 16 * 512;              // 16KB per array per tile
constexpr int BATCH_SHORTS = TILES * TILE_SHORTS;   // 262144

__device__ __forceinline__ unsigned short f2bf(float x) {
    unsigned u = __float_as_uint(x);
    u = (u + 0x7FFFu + ((u >> 16) & 1u)) >> 16;   // RNE
    return (unsigned short)u;
}
__device__ __forceinline__ float bf2f(unsigned short h) {
    return __uint_as_float(((unsigned)h) << 16);
}
__device__ __forceinline__ unsigned short f2h(float x) {
    union { _Float16 h; unsigned short s; } u;
    u.h = (_Float16)x;
    return u.s;
}
__device__ __forceinline__ unsigned pack_bf16(float lo, float hi) {
    __hip_bfloat162 r = __float22bfloat162_rn(make_float2(lo, hi));
    union { __hip_bfloat162 b; unsigned u; } c;
    c.b = r;
    return c.u;
}
__device__ __forceinline__ float ex2(float x) {
#if __has_builtin(__builtin_amdgcn_exp2f)
    return __builtin_amdgcn_exp2f(x);
#else
    return exp2f(x);
#endif
}

// -------- prep: K -> fp16 A-frag order, V -> bf16 B-frag order (32x32x16) ---
// K chunk c = kkq*4+ks : [lane][j] = K[t*128 + kkq*32 + (lane&31)][ks*16 + (lane>>5)*8 + j]
// V chunk c = ss*2+dt  : [lane][j] = V[t*128 + ss*16 + (lane>>5)*8 + j][dt*32 + (lane&31)]
__global__ __launch_bounds__(256) void prep2(
    const float* __restrict__ k, const float* __restrict__ v,
    unsigned short* __restrict__ kf, unsigned short* __restrict__ vf)
{
    __shared__ unsigned short tile[128 * 72];   // row stride 72 halves (pad)
    const int tid   = threadIdx.x;
    const int which = blockIdx.x & 1;           // 0 = K, 1 = V
    const int t     = (blockIdx.x >> 1) & 31;
    const int b     = blockIdx.x >> 6;
    const float* src = (which ? v : k) + ((size_t)b * S + t * BN) * D;

    #pragma unroll
    for (int i = 0; i < 8; ++i) {               // coalesced: 2048 float4s/block
        int f   = i * 256 + tid;
        int row = f >> 4;
        int c4  = (f & 15) << 2;
        float4 x = *(const float4*)(src + row * D + c4);
        s16x4 o;
        if (which) o = (s16x4){(short)f2bf(x.x), (short)f2bf(x.y),
                               (short)f2bf(x.z), (short)f2bf(x.w)};
        else       o = (s16x4){(short)f2h(x.x), (short)f2h(x.y),
                               (short)f2h(x.z), (short)f2h(x.w)};
        *(s16x4*)&tile[row * 72 + c4] = o;
    }
    __syncthreads();

    const int lane = tid & 63;
    unsigned short* dst = (which ? vf : kf) + (size_t)b * BATCH_SHORTS + t * TILE_SHORTS;
    #pragma unroll
    for (int i = 0; i < 4; ++i) {
        int c = (tid >> 6) * 4 + i;             // chunk 0..15
        s16x8 o;
        if (which == 0) {
            int row = (c >> 2) * 32 + (lane & 31);
            int dc  = (c & 3) * 16 + (lane >> 5) * 8;
            o = *(const s16x8*)&tile[row * 72 + dc];     // b128, aligned
        } else {
            int r0 = (c >> 1) * 16 + (lane >> 5) * 8;
            int dc = (c & 1) * 32 + (lane & 31);
            #pragma unroll
            for (int j = 0; j < 8; ++j) o[j] = (short)tile[(r0 + j) * 72 + dc];
        }
        *(s16x8*)(dst + c * 512 + lane * 8) = o;         // coalesced b128
    }
}

// ---------------- main: 128 q-rows per block, one kk-half per block --------
__global__ __launch_bounds__(512, 2) void attn_main4(
    const float* __restrict__ q, const unsigned short* __restrict__ kf,
    const unsigned short* __restrict__ vf, float* __restrict__ partial)
{
    __shared__ unsigned short smem[2 * 2 * TILE_SHORTS];   // 64KB: 2 x (K 16K | V 16K)

    const int tid = threadIdx.x, lane = tid & 63, w = tid >> 6;
    const int h = lane >> 5, m5 = lane & 31;
    const int mh = w & 1, kkq = w >> 1;         // m-half (64 rows), kk-quarter
    const int b = blockIdx.y, q0 = blockIdx.x * QROWS;
    const int kh = blockIdx.z;                  // kk-half 0/1
    const int t0 = kh * HALF_TILES;

    const unsigned short* kfb = kf + (size_t)b * BATCH_SHORTS;
    const unsigned short* vfb = vf + (size_t)b * BATCH_SHORTS;

    // Q B-frags fp16, pre-scaled by log2(e) so exp(s) = exp2(s').
    // B[k=h*8+j][n=m5] = log2e * Q[q0+mh*64+mt*32+m5][ks*16+h*8+j]
    const float LOG2E = 1.4426950408889634f;
    h16x8 qf[2][4];   // [mt][ks]
    #pragma unroll
    for (int mt = 0; mt < 2; ++mt) {
        const float* qrow = q + ((size_t)b * S + q0 + mh * 64 + mt * 32 + m5) * D + h * 8;
        #pragma unroll
        for (int ks = 0; ks < 4; ++ks) {
            float4 a = *(const float4*)(qrow + ks * 16);
            float4 c = *(const float4*)(qrow + ks * 16 + 4);
            qf[mt][ks] = (h16x8){
                (_Float16)(a.x * LOG2E), (_Float16)(a.y * LOG2E),
                (_Float16)(a.z * LOG2E), (_Float16)(a.w * LOG2E),
                (_Float16)(c.x * LOG2E), (_Float16)(c.y * LOG2E),
                (_Float16)(c.z * LOG2E), (_Float16)(c.w * LOG2E)};
        }
    }

    fx16 oacc[2][2] = {};   // [mt][dt], partial over (kk-quarter, kk-half)

    // Per wave, per tile: K chunks {w, 8+w} issued FIRST, then V chunks
    // {w, 8+w}. In-order vmcnt retirement makes vmcnt(2) == "my K landed".
    auto issue = [&](int t, int bi) {
        unsigned short* base = &smem[bi * 2 * TILE_SHORTS];
        #pragma unroll
        for (int ii = 0; ii < 4; ++ii) {                 // ii<2: K, else V
            int c = (ii & 1) * 8 + w;                    // chunk 0..15
            const unsigned short* g = (ii < 2 ? kfb : vfb)
                + (size_t)t * TILE_SHORTS + c * 512 + lane * 8;
            unsigned short* l = base + (ii < 2 ? 0 : TILE_SHORTS) + c * 512 + lane * 8;
            __builtin_amdgcn_global_load_lds(
                (const __attribute__((address_space(1))) unsigned int*)g,
                (__attribute__((address_space(3))) unsigned int*)l, 16, 0, 0);
        }
    };

    issue(t0, 0);

    for (int i = 0; i < HALF_TILES; ++i) {
        const int bi = i & 1;
        // K-wait: own K(i) landed (2 newer V(i) may still fly). The barrier
        // proves (a) every wave's K(i) landed, (b) all waves finished iter
        // i-1 entirely -> buffer bi^1 is reusable.
        __asm__ volatile("" ::: "memory");
        __builtin_amdgcn_s_waitcnt(0x0F72);   // vmcnt(2)
        __builtin_amdgcn_s_barrier();
        __asm__ volatile("" ::: "memory");
        if (i + 1 < HALF_TILES) issue(t0 + i + 1, bi ^ 1);

        const unsigned short* kb = &smem[bi * 2 * TILE_SHORTS];
        const unsigned short* vb = kb + TILE_SHORTS;

        // ---- GEMM1 (fp16 32x32x16): Sc^T[kk 32][m 32] x2 mt, d=64 ----
        // Reads K only; V(i) + tile i+1 DMA overlap with this phase.
        fx16 sa[2] = {};
        #pragma unroll
        for (int ks = 0; ks < 4; ++ks) {
            h16x8 a = *(const h16x8*)(kb + (kkq * 4 + ks) * 512 + lane * 8);
            #pragma unroll
            for (int mt = 0; mt < 2; ++mt)
                sa[mt] = __builtin_amdgcn_mfma_f32_32x32x16_f16(a, qf[mt][ks], sa[mt], 0, 0, 0);
        }

        // ---- P = exp2(Sc^T') in regs, bf16-pair packed ----
        // C-layout: kk = (r&3) + 8*(r>>2) + 4*h, m = m5. Pair rp packs regs
        // {2rp, 2rp+1}.
        unsigned p01[2][8];
        #pragma unroll
        for (int mt = 0; mt < 2; ++mt)
            #pragma unroll
            for (int rp = 0; rp < 8; ++rp)
                p01[mt][rp] = pack_bf16(ex2(sa[mt][2 * rp]), ex2(sa[mt][2 * rp + 1]));

        // ---- C-layout -> GEMM2 A-layout: cross-half exchange ----
        union frag { unsigned u[4]; s16x8 v; };
        frag A[2][2];   // [mt][u]
        #pragma unroll
        for (int mt = 0; mt < 2; ++mt) {
#if __has_builtin(__builtin_amdgcn_permlane32_swap)
            typedef unsigned uix2 __attribute__((ext_vector_type(2)));
            uix2 r0 = __builtin_amdgcn_permlane32_swap(p01[mt][0], p01[mt][2], false, false);
            uix2 r1 = __builtin_amdgcn_permlane32_swap(p01[mt][1], p01[mt][3], false, false);
            A[mt][0].u[0] = r0.x; A[mt][0].u[1] = r1.x;
            A[mt][0].u[2] = r0.y; A[mt][0].u[3] = r1.y;
            uix2 r2 = __builtin_amdgcn_permlane32_swap(p01[mt][4], p01[mt][6], false, false);
            uix2 r3 = __builtin_amdgcn_permlane32_swap(p01[mt][5], p01[mt][7], false, false);
            A[mt][1].u[0] = r2.x; A[mt][1].u[1] = r3.x;
            A[mt][1].u[2] = r2.y; A[mt][1].u[3] = r3.y;
#else
            unsigned sw[8];
            #pragma unroll
            for (int rp = 0; rp < 8; ++rp)
                sw[rp] = (unsigned)__shfl_xor((int)p01[mt][rp], 32, 64);
            A[mt][0].u[0] = h ? sw[2]        : p01[mt][0];
            A[mt][0].u[1] = h ? sw[3]        : p01[mt][1];
            A[mt][0].u[2] = h ? p01[mt][2]   : sw[0];
            A[mt][0].u[3] = h ? p01[mt][3]   : sw[1];
            A[mt][1].u[0] = h ? sw[6]        : p01[mt][4];
            A[mt][1].u[1] = h ? sw[7]        : p01[mt][5];
            A[mt][1].u[2] = h ? p01[mt][6]   : sw[4];
            A[mt][1].u[3] = h ? p01[mt][7]   : sw[5];
#endif
        }

        // V-wait: own V(i) landed. Outstanding here = V(i)[2] + K(i+1)[2] +
        // V(i+1)[2] = 6 -> vmcnt(4) retires the oldest 2 = V(i). Last iter
        // has nothing newer in flight -> vmcnt(0). Barrier proves all waves'
        // V(i) landed before any wave reads vb.
        __asm__ volatile("" ::: "memory");
        if (i + 1 < HALF_TILES) {
            __builtin_amdgcn_s_waitcnt(0x0F74);   // vmcnt(4)
        } else {
            __builtin_amdgcn_s_waitcnt(0x0F70);   // vmcnt(0)
        }
        __builtin_amdgcn_s_barrier();
        __asm__ volatile("" ::: "memory");

        // ---- GEMM2 (bf16 32x32x16): O += P*V over this wave's 32 kk ----
        #pragma unroll
        for (int u = 0; u < 2; ++u) {
            int ss = kkq * 2 + u;                        // 16-kk step in tile
            #pragma unroll
            for (int dt = 0; dt < 2; ++dt) {
                s16x8 vv = *(const s16x8*)(vb + (ss * 2 + dt) * 512 + lane * 8);
                #pragma unroll
                for (int mt = 0; mt < 2; ++mt)
                    oacc[mt][dt] = __builtin_amdgcn_mfma_f32_32x32x16_bf16(
                        A[mt][u].v, vv, oacc[mt][dt], 0, 0, 0);
            }
        }
    }

    // ---- epilogue: reduce 4 kk-quarters per m-half; 2 dt rounds (48KB) ----
    __syncthreads();                     // all DMA drained (vmcnt(0) last iter)
    float* scratch = (float*)smem;
    float* pout = partial + ((size_t)kh * gridDim.y + b) * S * D;
    #pragma unroll
    for (int dt = 0; dt < 2; ++dt) {
        if (kkq > 0) {
            float* dst = scratch + (size_t)(mh * 3 + (kkq - 1)) * 2048;
            #pragma unroll
            for (int mt = 0; mt < 2; ++mt)
                #pragma unroll
                for (int r = 0; r < 16; ++r)
                    dst[(mt * 16 + r) * 64 + lane] = oacc[mt][dt][r];
        }
        __syncthreads();
        if (kkq == 0) {
            #pragma unroll
            for (int mt = 0; mt < 2; ++mt)
                #pragma unroll
                for (int r = 0; r < 16; ++r) {
                    float val = oacc[mt][dt][r];
                    #pragma unroll
                    for (int p = 0; p < 3; ++p)
                        val += scratch[(size_t)(mh * 3 + p) * 2048 + (mt * 16 + r) * 64 + lane];
                    int row = q0 + mh * 64 + mt * 32 + (r & 3) + 8 * (r >> 2) + 4 * h;
                    pout[(size_t)row * D + dt * 32 + m5] = val;
                }
        }
        __syncthreads();
    }
}

// ---------------- final reduce: out = partial[0] + partial[1] ----------------
__global__ __launch_bounds__(256) void reduce_out(
    const float4* __restrict__ p0, const float4* __restrict__ p1,
    float4* __restrict__ o, int n4)
{
    int i = blockIdx.x * 256 + threadIdx.x;
    if (i < n4) {
        float4 a = p0[i], b = p1[i];
        o[i] = make_float4(a.x + b.x, a.y + b.y, a.z + b.z, a.w + b.w);
    }
}

// ---------------- fallback (known-good round-2 kernel) ----------------
__global__ __launch_bounds__(1024) void attn_fallback(
    const float* __restrict__ q, const float* __restrict__ k,
    const float* __restrict__ v, float* __restrict__ out)
{
    __shared__ unsigned short Kh[64][72];
    __shared__ unsigned short Kl[64][72];
    __shared__ unsigned short Vt[64][68];
    __shared__ unsigned short Pf[64][72];

    const int tid = threadIdx.x, lane = tid & 63, wave = tid >> 6;
    const int quad = lane >> 4, tq = lane & 15;
    const int kkb = wave & 3, mba = wave >> 2;
    const int b = blockIdx.y, q0 = blockIdx.x * 64;
    const float* qb = q + (size_t)b * S * D;
    const float* kb = k + (size_t)b * S * D;
    const float* vb = v + (size_t)b * S * D;
    float* ob = out + (size_t)b * S * D;

    s16x8 qh[2], ql[2];
    {
        const float* qrow = qb + (size_t)(q0 + mba * 16 + tq) * D;
        #pragma unroll
        for (int ks = 0; ks < 2; ++ks) {
            const float* src = qrow + ks * 32 + quad * 8;
            float4 f0 = *(const float4*)src;
            float4 f1 = *(const float4*)(src + 4);
            float f[8] = {f0.x, f0.y, f0.z, f0.w, f1.x, f1.y, f1.z, f1.w};
            #pragma unroll
            for (int j = 0; j < 8; ++j) {
                unsigned short hh = f2bf(f[j]);
                qh[ks][j] = (short)hh;
                ql[ks][j] = (short)f2bf(f[j] - bf2f(hh));
            }
        }
    }
    fx4 oacc = {0.f, 0.f, 0.f, 0.f};
    const int krow = tid >> 4, kc4 = (tid & 15) << 2;
    const int vd = tid & 63, vk = (tid >> 6) << 2;

    for (int t = 0; t < S / 64; ++t) {
        __syncthreads();
        const float* kt = kb + (size_t)(t * 64 + krow) * D;
        const float* vt = vb + (size_t)(t * 64 + vk) * D;
        {
            float4 kv = *(const float4*)(kt + kc4);
            unsigned short h0 = f2bf(kv.x), h1 = f2bf(kv.y), h2 = f2bf(kv.z), h3 = f2bf(kv.w);
            s16x4 a = {(short)h0, (short)h1, (short)h2, (short)h3};
            s16x4 l4 = {(short)f2bf(kv.x - bf2f(h0)), (short)f2bf(kv.y - bf2f(h1)),
                        (short)f2bf(kv.z - bf2f(h2)), (short)f2bf(kv.w - bf2f(h3))};
            *(s16x4*)&Kh[krow][kc4] = a;
            *(s16x4*)&Kl[krow][kc4] = l4;
            const float* vs = vt + vd;
            s16x4 vv = {(short)f2bf(vs[0]), (short)f2bf(vs[D]),
                        (short)f2bf(vs[2 * D]), (short)f2bf(vs[3 * D])};
            *(s16x4*)&Vt[vd][vk] = vv;
        }
        __syncthreads();
        fx4 sacc = {0.f, 0.f, 0.f, 0.f};
        #pragma unroll
        for (int ks = 0; ks < 2; ++ks) {
            s16x8 kah = *(const s16x8*)&Kh[kkb * 16 + tq][ks * 32 + quad * 8];
            s16x8 kal = *(const s16x8*)&Kl[kkb * 16 + tq][ks * 32 + quad * 8];
            sacc = __builtin_amdgcn_mfma_f32_16x16x32_bf16(kah, qh[ks], sacc, 0, 0, 0);
            sacc = __builtin_amdgcn_mfma_f32_16x16x32_bf16(kah, ql[ks], sacc, 0, 0, 0);
            sacc = __builtin_amdgcn_mfma_f32_16x16x32_bf16(kal, qh[ks], sacc, 0, 0, 0);
        }
        s16x4 pp = {(short)f2bf(__expf(sacc[0])), (short)f2bf(__expf(sacc[1])),
                    (short)f2bf(__expf(sacc[2])), (short)f2bf(__expf(sacc[3]))};
        *(s16x4*)&Pf[mba * 16 + tq][kkb * 16 + (quad << 2)] = pp;
        __syncthreads();
        #pragma unroll
        for (int ks = 0; ks < 2; ++ks) {
            s16x8 pa = *(const s16x8*)&Pf[mba * 16 + tq][ks * 32 + quad * 8];
            const unsigned short* vr = &Vt[kkb * 16 + tq][ks * 32 + quad * 8];
            s16x4 va = *(const s16x4*)vr;
            s16x4 vb2 = *(const s16x4*)(vr + 4);
            s16x8 vfull = __builtin_shufflevector(va, vb2, 0, 1, 2, 3, 4, 5, 6, 7);
            oacc = __builtin_amdgcn_mfma_f32_16x16x32_bf16(pa, vfull, oacc, 0, 0, 0);
        }
    }
    #pragma unroll
    for (int r = 0; r < 4; ++r)
        ob[(size_t)(q0 + mba * 16 + quad * 4 + r) * D + kkb * 16 + tq] = oacc[r];
}

extern "C" void kernel_launch(void* const* d_in, const int* in_sizes, int n_in,
                              void* d_out, int out_size, void* d_ws, size_t ws_size,
                              hipStream_t stream) {
    const float* q = (const float*)d_in[0];
    const float* k = (const float*)d_in[1];
    const float* v = (const float*)d_in[2];
    float* out = (float*)d_out;
    const int nbatch = in_sizes[0] / (S * D);   // 4
    const size_t elems = (size_t)nbatch * S * D;

    // ws: kf (fp16, 2MB) | vf (bf16, 2MB) | partial[2] (fp32, 8MB) = 12MB
    const size_t need = elems * 2 * 2 + elems * 2 * 4;
    if (nbatch == 4 && ws_size >= need && d_ws != nullptr) {
        unsigned short* kf = (unsigned short*)d_ws;
        unsigned short* vf = kf + elems;
        float* partial = (float*)(vf + elems);

        prep2<<<nbatch * TILES * 2, 256, 0, stream>>>(k, v, kf, vf);
        dim3 grid(S / QROWS, nbatch, 2);
        attn_main4<<<grid, 512, 0, stream>>>(q, kf, vf, partial);
        const int n4 = (int)(elems / 4);
        reduce_out<<<(n4 + 255) / 256, 256, 0, stream>>>(
            (const float4*)partial, (const float4*)(partial + elems),
            (float4*)out, n4);
    } else {
        dim3 grid(S / 64, nbatch);
        attn_fallback<<<grid, 1024, 0, stream>>>(q, k, v, out);
    }
}